// Round 3
// 76.797 us; speedup vs baseline: 1.0179x; 1.0179x over previous
//
#include <hip/hip_runtime.h>
#include <math.h>

// Problem constants (mirrors reference)
#define BATCH    1024
#define NLM      13
#define GRID_HW  256
// ELL_W=1, GAU_W=1, REG_W=0.3, VIS_W=0.01
// SIG_MAJ=0.15 SIG_MIN=0.05 ELL_RADIUS=0.3
// SIGMA=0.1 GAU_RADIUS=0.2 SHARP=1.0 EPS=1e-8
//
// Single plain launch (cooperative launch fails under the harness's
// graph/stream capture -> kernel never ran in R1). Each block owns one
// batch: full r<=0.3 bbox with a 16x16 tile (rows step 16, fixed 10-wide
// fully-unrolled masked column loop: max bbox width 155 -> ceil(155/16)=10).
// Separable exponentials: per-thread column terms (u^2, exp(cMaj u^2),
// exp(cGau u^2), dxp^2) computed once; row terms hoisted. Block-reduce ->
// per-batch scalar t_b (ratios + smooth-L1 + BCE folded) -> one
// atomicAdd(out, t_b) per block. Harness memsets out to 0 before each
// launch, so the atomic sum starts clean. Float-atomic ordering noise
// ~1e-7, threshold 1.1e-2.

#define KCOLS 10

__global__ __launch_bounds__(256) void fused_loss_kernel(
    const float* __restrict__ pred_lm,   // (B,13,2)
    const float* __restrict__ tgt_lm,    // (B,13,2)
    const float* __restrict__ pred_vis,  // (B,13)
    const float* __restrict__ tgt_vis,   // (B,13)
    float* __restrict__ out)             // (1), pre-zeroed by harness
{
    const int b    = blockIdx.x;
    const int lane = threadIdx.x & 63;
    const int wave = threadIdx.x >> 6;
    const int tx   = threadIdx.x & 15;
    const int ty   = threadIdx.x >> 4;

    __shared__ float sd[4][4];

    const float btx = tgt_lm[b * (NLM * 2) + 0];
    const float bty = tgt_lm[b * (NLM * 2) + 1];
    const float bpx = pred_lm[b * (NLM * 2) + 0];
    const float bpy = pred_lm[b * (NLM * 2) + 1];
    const float vis = tgt_vis[b * NLM];

    float s_gw = 0.0f, s_gwd = 0.0f, s_ew = 0.0f, s_ewd = 0.0f;

    if (vis >= 0.5f) {
        const float R = 0.3f;
        const int c0 = max(0, (int)floorf((btx - R) * 255.0f));
        const int c1 = min(GRID_HW - 1, (int)ceilf((btx + R) * 255.0f));
        const int r0 = max(0, (int)floorf((bty - R) * 255.0f));
        const int r1 = min(GRID_HW - 1, (int)ceilf((bty + R) * 255.0f));

        const float inv255 = 1.0f / 255.0f;
        const float du     = 16.0f * inv255;
        const float cMaj   = -0.5f / (0.15f * 0.15f);
        const float cMin   = -0.5f / (0.05f * 0.05f);
        const float cGau   = -50.0f;
        const float ell_r2 = 0.09f;
        const float gau_r2 = 0.04f;
        const float dxo    = btx - bpx;
        const float u0     = (float)(c0 + tx) * inv255 - btx;

        // Per-thread column terms (constant across rows).
        float u2a[KCOLS], emx[KCOLS], egx[KCOLS], dxp2[KCOLS];
        #pragma unroll
        for (int k = 0; k < KCOLS; ++k) {
            float u  = u0 + (float)k * du;
            bool ok  = (c0 + tx + 16 * k) <= c1;  // beyond c1 => dt > R exactly
            float u2 = u * u;
            u2a[k]  = u2;
            emx[k]  = ok ? __expf(cMaj * u2) : 0.0f;
            egx[k]  = ok ? __expf(cGau * u2) : 0.0f;
            float dxp = u + dxo;
            dxp2[k] = dxp * dxp;
        }

        for (int ry = r0 + ty; ry <= r1; ry += 16) {
            const float y    = (float)ry * inv255;
            const float v    = y - bty;
            const float v2   = v * v;
            const float dyp  = y - bpy;
            const float dyp2 = dyp * dyp;
            const float eyE  = __expf(cMin * v2);  // row factor, ellipsoid
            const float gyE  = __expf(cGau * v2);  // row factor, gaussian

            #pragma unroll
            for (int k = 0; k < KCOLS; ++k) {
                float dt2 = u2a[k] + v2;
                float dp  = sqrtf(dxp2[k] + dyp2);
                float ew  = (dt2 <= ell_r2) ? emx[k] * eyE : 0.0f;
                float gw  = (dt2 <= gau_r2) ? egx[k] * gyE : 0.0f;
                s_ew  += ew;
                s_ewd  = fmaf(ew, dp, s_ewd);
                s_gw  += gw;
                s_gwd  = fmaf(gw, dp, s_gwd);
            }
        }
    }

    // Wave reduce, then cross-wave via LDS.
    #pragma unroll
    for (int off = 32; off > 0; off >>= 1) {
        s_gw  += __shfl_down(s_gw,  off);
        s_gwd += __shfl_down(s_gwd, off);
        s_ew  += __shfl_down(s_ew,  off);
        s_ewd += __shfl_down(s_ewd, off);
    }
    if (lane == 0) {
        sd[wave][0] = s_gw;
        sd[wave][1] = s_gwd;
        sd[wave][2] = s_ew;
        sd[wave][3] = s_ewd;
    }
    __syncthreads();

    if (threadIdx.x == 0) {
        float gw  = sd[0][0] + sd[1][0] + sd[2][0] + sd[3][0];
        float gwd = sd[0][1] + sd[1][1] + sd[2][1] + sd[3][1];
        float ew  = sd[0][2] + sd[1][2] + sd[2][2] + sd[3][2];
        float ewd = sd[0][3] + sd[1][3] + sd[2][3] + sd[3][3];

        // Per-batch regression + BCE (independent of visibility).
        float adx = fabsf(bpx - btx);
        float ady = fabsf(bpy - bty);
        float rx  = (adx < 1.0f) ? (0.5f * adx * adx) : (adx - 0.5f);
        float ry2 = (ady < 1.0f) ? (0.5f * ady * ady) : (ady - 0.5f);
        float p   = fminf(fmaxf(pred_vis[b * NLM], 1e-7f), 1.0f - 1e-7f);
        float bce = -(vis * __logf(p) + (1.0f - vis) * __logf(1.0f - p));

        const float EPSf = 1e-8f;
        float t_b = (ewd / (ew + EPSf) + gwd / (gw + EPSf)) * (1.0f / 1024.0f)
                  + 0.3f  * (rx + ry2) * (1.0f / 2048.0f)
                  + 0.01f * bce        * (1.0f / 1024.0f);
        atomicAdd(out, t_b);   // device-scope by default on CDNA
    }
}

extern "C" void kernel_launch(void* const* d_in, const int* in_sizes, int n_in,
                              void* d_out, int out_size, void* d_ws, size_t ws_size,
                              hipStream_t stream) {
    const float* pred_lm  = (const float*)d_in[0];  // (1024,13,2)
    const float* tgt_lm   = (const float*)d_in[1];  // (1024,13,2)
    const float* pred_vis = (const float*)d_in[2];  // (1024,13)
    const float* tgt_vis  = (const float*)d_in[3];  // (1024,13)
    float* out = (float*)d_out;

    fused_loss_kernel<<<BATCH, 256, 0, stream>>>(
        pred_lm, tgt_lm, pred_vis, tgt_vis, out);
}

// Round 4
// 71.825 us; speedup vs baseline: 1.0884x; 1.0692x over previous
//
#include <hip/hip_runtime.h>
#include <math.h>

// Problem constants (mirrors reference)
#define BATCH    1024
#define NLM      13
#define GRID_HW  256
// ELL_W=1, GAU_W=1, REG_W=0.3, VIS_W=0.01
// SIG_MAJ=0.15 SIG_MIN=0.05 ELL_RADIUS=0.3
// SIGMA=0.1 GAU_RADIUS=0.2 SHARP=1.0 EPS=1e-8
//
// Single plain launch; each block owns one batch: full r<=0.3 bbox with a
// 16x16 tile (rows step 16; 10-wide fully-unrolled column loop with
// block-uniform guards 16k<=wid skipping wholly-dead trailing bodies —
// static array indexing preserved, no scratch). Separable exponentials:
// per-thread column terms (u^2, exp(cMaj u^2), exp(cGau u^2), dxp^2)
// computed once; row terms hoisted. dp via __builtin_amdgcn_sqrtf (raw
// v_sqrt_f32, ~1 ulp — avoids the precise-sqrt fixup sequence; threshold
// is 1.1e-2). Block-reduce -> per-batch scalar t_b (ratios + smooth-L1 +
// BCE folded) -> one atomicAdd(out, t_b) per block (harness pre-zeroes
// out; float-ordering noise ~1e-7).

#define KCOLS 10

__global__ __launch_bounds__(256) void fused_loss_kernel(
    const float* __restrict__ pred_lm,   // (B,13,2)
    const float* __restrict__ tgt_lm,    // (B,13,2)
    const float* __restrict__ pred_vis,  // (B,13)
    const float* __restrict__ tgt_vis,   // (B,13)
    float* __restrict__ out)             // (1), pre-zeroed by harness
{
    const int b    = blockIdx.x;
    const int lane = threadIdx.x & 63;
    const int wave = threadIdx.x >> 6;
    const int tx   = threadIdx.x & 15;
    const int ty   = threadIdx.x >> 4;

    __shared__ float sd[4][4];

    const float btx = tgt_lm[b * (NLM * 2) + 0];
    const float bty = tgt_lm[b * (NLM * 2) + 1];
    const float bpx = pred_lm[b * (NLM * 2) + 0];
    const float bpy = pred_lm[b * (NLM * 2) + 1];
    const float vis = tgt_vis[b * NLM];

    float s_gw = 0.0f, s_gwd = 0.0f, s_ew = 0.0f, s_ewd = 0.0f;

    if (vis >= 0.5f) {
        const float R = 0.3f;
        const int c0 = max(0, (int)floorf((btx - R) * 255.0f));
        const int c1 = min(GRID_HW - 1, (int)ceilf((btx + R) * 255.0f));
        const int r0 = max(0, (int)floorf((bty - R) * 255.0f));
        const int r1 = min(GRID_HW - 1, (int)ceilf((bty + R) * 255.0f));
        const int wid = c1 - c0;  // max 154 -> bodies needed = wid/16+1 <= 10

        const float inv255 = 1.0f / 255.0f;
        const float du     = 16.0f * inv255;
        const float cMaj   = -0.5f / (0.15f * 0.15f);
        const float cMin   = -0.5f / (0.05f * 0.05f);
        const float cGau   = -50.0f;
        const float ell_r2 = 0.09f;
        const float gau_r2 = 0.04f;
        const float dxo    = btx - bpx;
        const float u0     = (float)(c0 + tx) * inv255 - btx;

        // Per-thread column terms (constant across rows).
        float u2a[KCOLS], emx[KCOLS], egx[KCOLS], dxp2[KCOLS];
        #pragma unroll
        for (int k = 0; k < KCOLS; ++k) {
            float u  = u0 + (float)k * du;
            bool ok  = (c0 + tx + 16 * k) <= c1;  // beyond c1 => dt > R exactly
            float u2 = u * u;
            u2a[k]  = u2;
            emx[k]  = ok ? __expf(cMaj * u2) : 0.0f;
            egx[k]  = ok ? __expf(cGau * u2) : 0.0f;
            float dxp = u + dxo;
            dxp2[k] = dxp * dxp;
        }

        for (int ry = r0 + ty; ry <= r1; ry += 16) {
            const float y    = (float)ry * inv255;
            const float v    = y - bty;
            const float v2   = v * v;
            const float dyp  = y - bpy;
            const float dyp2 = dyp * dyp;
            const float eyE  = __expf(cMin * v2);  // row factor, ellipsoid
            const float gyE  = __expf(cGau * v2);  // row factor, gaussian

            #pragma unroll
            for (int k = 0; k < KCOLS; ++k) {
                // Block-uniform guard: column block k exists for some tx.
                // (Trailing bodies are wholly masked-dead; skip their ALU.)
                if (16 * k <= wid) {
                    float dt2 = u2a[k] + v2;
                    float d2  = dxp2[k] + dyp2;
                    float dp  = __builtin_amdgcn_sqrtf(d2);  // raw v_sqrt_f32
                    float ew  = (dt2 <= ell_r2) ? emx[k] * eyE : 0.0f;
                    float gw  = (dt2 <= gau_r2) ? egx[k] * gyE : 0.0f;
                    s_ew  += ew;
                    s_ewd  = fmaf(ew, dp, s_ewd);
                    s_gw  += gw;
                    s_gwd  = fmaf(gw, dp, s_gwd);
                }
            }
        }
    }

    // Wave reduce, then cross-wave via LDS.
    #pragma unroll
    for (int off = 32; off > 0; off >>= 1) {
        s_gw  += __shfl_down(s_gw,  off);
        s_gwd += __shfl_down(s_gwd, off);
        s_ew  += __shfl_down(s_ew,  off);
        s_ewd += __shfl_down(s_ewd, off);
    }
    if (lane == 0) {
        sd[wave][0] = s_gw;
        sd[wave][1] = s_gwd;
        sd[wave][2] = s_ew;
        sd[wave][3] = s_ewd;
    }
    __syncthreads();

    if (threadIdx.x == 0) {
        float gw  = sd[0][0] + sd[1][0] + sd[2][0] + sd[3][0];
        float gwd = sd[0][1] + sd[1][1] + sd[2][1] + sd[3][1];
        float ew  = sd[0][2] + sd[1][2] + sd[2][2] + sd[3][2];
        float ewd = sd[0][3] + sd[1][3] + sd[2][3] + sd[3][3];

        // Per-batch regression + BCE (independent of visibility).
        float adx = fabsf(bpx - btx);
        float ady = fabsf(bpy - bty);
        float rx  = (adx < 1.0f) ? (0.5f * adx * adx) : (adx - 0.5f);
        float ry2 = (ady < 1.0f) ? (0.5f * ady * ady) : (ady - 0.5f);
        float p   = fminf(fmaxf(pred_vis[b * NLM], 1e-7f), 1.0f - 1e-7f);
        float bce = -(vis * __logf(p) + (1.0f - vis) * __logf(1.0f - p));

        const float EPSf = 1e-8f;
        float t_b = (ewd / (ew + EPSf) + gwd / (gw + EPSf)) * (1.0f / 1024.0f)
                  + 0.3f  * (rx + ry2) * (1.0f / 2048.0f)
                  + 0.01f * bce        * (1.0f / 1024.0f);
        atomicAdd(out, t_b);   // device-scope by default on CDNA
    }
}

extern "C" void kernel_launch(void* const* d_in, const int* in_sizes, int n_in,
                              void* d_out, int out_size, void* d_ws, size_t ws_size,
                              hipStream_t stream) {
    const float* pred_lm  = (const float*)d_in[0];  // (1024,13,2)
    const float* tgt_lm   = (const float*)d_in[1];  // (1024,13,2)
    const float* pred_vis = (const float*)d_in[2];  // (1024,13)
    const float* tgt_vis  = (const float*)d_in[3];  // (1024,13)
    float* out = (float*)d_out;

    fused_loss_kernel<<<BATCH, 256, 0, stream>>>(
        pred_lm, tgt_lm, pred_vis, tgt_vis, out);
}